// Round 7
// baseline (291.493 us; speedup 1.0000x reference)
//
#include <hip/hip_runtime.h>
#include <hip/hip_bf16.h>
#include <stdint.h>

// ---------------------------------------------------------------------------
// AFT-Full on MI355X.  exp_wb == 1 exactly (max over singleton axis), so
// num/den are plain sums over t.  GEMMs: 256^2 tile, FOUR waves (2x2), each
// wave owns a 128x128 output (256-f32 acc).  One barrier + one vmcnt(0) per
// K-tile; whole next tile burst-staged at tile start (~full-tile slack);
// ds_reads pipelined with counted lgkmcnt.  LDS read amplification 4x (was
// 6x with 8 waves), sync cost 1/4.
// ---------------------------------------------------------------------------

typedef __bf16 vbf16x8 __attribute__((ext_vector_type(8)));
typedef float  vf32x4  __attribute__((ext_vector_type(4)));

#define BB   64
#define TT   576
#define CC   768
#define HID  576
#define NQKV 1792              /* 3*576=1728 padded to 14*128 (stores padded cols; unused) */
#define MR   (BB*TT)           /* 36864 rows */

__device__ __forceinline__ unsigned short f2bf(float f) {
    union { float f; unsigned u; } v; v.f = f;
    unsigned r = v.u + 0x7fffu + ((v.u >> 16) & 1u);   // RNE
    return (unsigned short)(r >> 16);
}
__device__ __forceinline__ float bf2f(unsigned short b) {
    union { unsigned u; float f; } v; v.u = ((unsigned)b) << 16;
    return v.f;
}

// ---- prep: transpose+convert weights to bf16 [N][K], build fused qkv bias --
__global__ void prep_kernel(const float* __restrict__ Wq, const float* __restrict__ Wk,
                            const float* __restrict__ Wv, const float* __restrict__ Wo,
                            const float* __restrict__ bq, const float* __restrict__ bk,
                            const float* __restrict__ bv,
                            unsigned short* __restrict__ WqkvT,   // [1792][768]
                            unsigned short* __restrict__ WoT,     // [768][576]
                            float* __restrict__ bqkv)             // [1792]
{
    int idx = blockIdx.x * 256 + threadIdx.x;
    const int NW1 = NQKV * CC;          // 1792*768
    const int NW2 = CC * HID;           // 768*576
    if (idx < NW1) {
        int n = idx / CC, k = idx % CC;
        float v = 0.f;
        if      (n < 576)  v = Wq[k * HID + n];
        else if (n < 1152) v = Wk[k * HID + (n - 576)];
        else if (n < 1728) v = Wv[k * HID + (n - 1152)];
        WqkvT[idx] = f2bf(v);
    } else if (idx < NW1 + NW2) {
        int i = idx - NW1;
        int c = i / HID, h = i % HID;
        WoT[i] = f2bf(Wo[h * CC + c]);
    } else if (idx < NW1 + NW2 + NQKV) {
        int n = idx - NW1 - NW2;
        float v = 0.f;
        if      (n < 576)  v = bq[n];
        else if (n < 1152) v = bk[n - 576];
        else if (n < 1728) v = bv[n - 1152];
        bqkv[n] = v;
    }
}

// ---- convert x (f32) -> bf16, vectorized 4/thread ---------------------------
__global__ void convx_kernel(const float* __restrict__ x, unsigned short* __restrict__ xb, int n4)
{
    int i = blockIdx.x * 256 + threadIdx.x;
    if (i >= n4) return;
    float4 a = ((const float4*)x)[i];
    uint2 o;
    o.x = (unsigned)f2bf(a.x) | ((unsigned)f2bf(a.y) << 16);
    o.y = (unsigned)f2bf(a.z) | ((unsigned)f2bf(a.w) << 16);
    ((uint2*)xb)[i] = o;
}

// ============================================================================
// 4-wave 256x256 GEMM.  A[M][K] bf16 rm, Bt[N][K] bf16 rm, C = A*B + bias.
// Per K-tile: burst-stage next tile (16 gload_lds) -> pipelined ds_reads with
// counted lgkmcnt -> 4 MFMA clusters of 32 -> vmcnt(0) + barrier.
// LDS source pre-swizzled (col16 ^= row&7); reads apply the same involution.
// ============================================================================

#define BARR()   asm volatile("s_barrier" ::: "memory")
#define LGKM(n)  do { asm volatile("s_waitcnt lgkmcnt(" #n ")" ::: "memory"); \
                      __builtin_amdgcn_sched_barrier(0); } while (0)
#define VMCNT0() asm volatile("s_waitcnt vmcnt(0)" ::: "memory")
#define PRIO1()  __builtin_amdgcn_s_setprio(1)
#define PRIO0()  do { __builtin_amdgcn_s_setprio(0); \
                      __builtin_amdgcn_sched_barrier(0); } while (0)

// stage a full 256x64 matrix tile: 8 passes x 256 threads x 16B = 32 KB
#define STG_MAT(BI, MAT, KT, G) do { \
    _Pragma("unroll") \
    for (int p = 0; p < 8; ++p) { \
        const unsigned short* _s = (G) + (size_t)(KT) * 64 + (size_t)p * 32 * ldk + soff; \
        __builtin_amdgcn_global_load_lds((const __attribute__((address_space(1))) void*)_s, \
            (__attribute__((address_space(3))) void*)&lds[BI][MAT][p * 2048 + tid * 8], 16, 0, 0); \
    } \
} while (0)

__device__ __forceinline__ void read4(const char* L, int base, int fr, int kg, vbf16x8 o[4][2]) {
#pragma unroll
    for (int m = 0; m < 4; ++m)
#pragma unroll
        for (int ks = 0; ks < 2; ++ks) {
            int R = base + m * 16 + fr;
            o[m][ks] = *(const vbf16x8*)(L + (size_t)R * 128 + ((((ks * 4 + kg) ^ (R & 7))) << 4));
        }
}

#define CLUSTER(AF, BF, MO, NO) do { \
    _Pragma("unroll") \
    for (int m = 0; m < 4; ++m) \
        _Pragma("unroll") \
        for (int n = 0; n < 4; ++n) \
            _Pragma("unroll") \
            for (int ks = 0; ks < 2; ++ks) \
                acc[(MO) + m][(NO) + n] = __builtin_amdgcn_mfma_f32_16x16x32_bf16( \
                    AF[m][ks], BF[n][ks], acc[(MO) + m][(NO) + n], 0, 0, 0); \
} while (0)

template <int EPI>   // 0: bf16 out, 1: f32 out
__global__ __launch_bounds__(256, 1) void gemm4w(const unsigned short* __restrict__ A,
                                                 const unsigned short* __restrict__ Bt,
                                                 void* __restrict__ Cv,
                                                 const float* __restrict__ bias,
                                                 int N, int ldk, int NT, int nbn)
{
    __shared__ unsigned short lds[2][2][16384];   // [buf][A/B][256*64] = 128 KiB
    int tid = threadIdx.x;
    int lane = tid & 63, wave = tid >> 6;
    int fr = lane & 15, kg = lane >> 4;
    int wm = wave >> 1, wn = wave & 1;

    // XCD-aware swizzle (grid % 8 == 0)
    int cpx = gridDim.x >> 3;
    int wg = (blockIdx.x & 7) * cpx + (blockIdx.x >> 3);
    int bm = wg / nbn, bn = wg % nbn;

    const unsigned short* Ag = A + (size_t)bm * 256 * ldk;
    const unsigned short* Bg = Bt + (size_t)bn * 256 * ldk;

    // staging source offset (pre-swizzled: col16 ^= row&7); rows advance by 32/pass
    size_t soff = (size_t)(tid >> 3) * ldk + (size_t)(((tid & 7) ^ ((tid >> 3) & 7)) * 8);

    vf32x4 acc[8][8] = {};
    vbf16x8 a0[4][2], a1[4][2], b0[4][2], b1[4][2];

    // prologue: tile0 -> buf0
    STG_MAT(0, 0, 0, Ag);
    STG_MAT(0, 1, 0, Bg);
    VMCNT0();
    BARR();

    for (int t = 0; t < NT; ++t) {
        int cur = t & 1;
        const char* LA = (const char*)lds[cur][0];
        const char* LB = (const char*)lds[cur][1];

        // issue reads a0,b0,b1; burst-stage next tile between them
        read4(LA, wm * 128, fr, kg, a0);
        read4(LB, wn * 128, fr, kg, b0);
        if (t + 1 < NT) {
            STG_MAT(cur ^ 1, 0, t + 1, Ag);
            STG_MAT(cur ^ 1, 1, t + 1, Bg);
        }
        read4(LB, wn * 128 + 64, fr, kg, b1);

        // C1: a0 x b0   (lgkm(8): a0,b0 drained; b1 still allowed in flight)
        LGKM(8); PRIO1(); CLUSTER(a0, b0, 0, 0); PRIO0();
        read4(LA, wm * 128 + 64, fr, kg, a1);
        // C2: a0 x b1   (lgkm(8): b1 drained; a1 in flight)
        LGKM(8); PRIO1(); CLUSTER(a0, b1, 0, 4); PRIO0();
        // C3+C4: a1 x b1, a1 x b0
        LGKM(0); PRIO1(); CLUSTER(a1, b1, 4, 4); CLUSTER(a1, b0, 4, 0); PRIO0();

        VMCNT0();   // own staging loads for t+1 landed (a full tile of slack)
        BARR();
    }

    // epilogue: C/D layout col = lane&15, row = (lane>>4)*4 + reg
    int row0 = bm * 256 + wm * 128 + kg * 4;
    int col0 = bn * 256 + wn * 128;
#pragma unroll
    for (int m = 0; m < 8; ++m) {
#pragma unroll
        for (int n = 0; n < 8; ++n) {
            int c = col0 + n * 16 + fr;
            float bb = bias[c];
            int r = row0 + m * 16;
#pragma unroll
            for (int j = 0; j < 4; ++j) {
                float v = acc[m][n][j] + bb;
                if (EPI == 0) ((unsigned short*)Cv)[(size_t)(r + j) * N + c] = f2bf(v);
                else          ((float*)Cv)[(size_t)(r + j) * N + c] = v;
            }
        }
    }
}

// ---- max over batch: maxk[t][h] = max_b k[b,t,h] ----------------------------
__global__ void maxk_kernel(const unsigned short* __restrict__ qkv, float* __restrict__ maxk)
{
    int idx = blockIdx.x * 256 + threadIdx.x;      // t*576 + h
    if (idx >= TT * HID) return;
    int t = idx / HID, h = idx % HID;
    const unsigned short* p = qkv + (size_t)t * NQKV + 576 + h;
    const size_t stride = (size_t)TT * NQKV;
    float m0 = -1e30f, m1 = -1e30f, m2 = -1e30f, m3 = -1e30f;
#pragma unroll 4
    for (int b = 0; b < BB; b += 4) {
        m0 = fmaxf(m0, bf2f(p[(size_t)(b + 0) * stride]));
        m1 = fmaxf(m1, bf2f(p[(size_t)(b + 1) * stride]));
        m2 = fmaxf(m2, bf2f(p[(size_t)(b + 2) * stride]));
        m3 = fmaxf(m3, bf2f(p[(size_t)(b + 3) * stride]));
    }
    maxk[idx] = fmaxf(fmaxf(m0, m1), fmaxf(m2, m3));
}

// ---- num/den partial sums over t (split into 4 chunks, no atomics) ---------
__global__ void numden_kernel(const unsigned short* __restrict__ qkv,
                              const float* __restrict__ maxk,
                              float* __restrict__ num_p, float* __restrict__ den_p)
{
    int b = blockIdx.x, tc = blockIdx.y, h = threadIdx.x;   // 576 threads
    float num = 0.f, den = 0.f;
    int t0 = tc * 144;
    for (int t = t0; t < t0 + 144; ++t) {
        const unsigned short* row = qkv + (size_t)(b * TT + t) * NQKV;
        float kk = bf2f(row[576 + h]);
        float vv = bf2f(row[1152 + h]);
        float e  = __expf(kk - maxk[t * HID + h]);
        den += e;
        num += e * vv;
    }
    int o = (tc * BB + b) * HID + h;
    num_p[o] = num;
    den_p[o] = den;
}

// ---- y = sigmoid(q) * num/den  (bf16, dense stride 576) --------------------
__global__ void y_kernel(const unsigned short* __restrict__ qkv,
                         const float* __restrict__ num_p, const float* __restrict__ den_p,
                         unsigned short* __restrict__ y)
{
    int idx = blockIdx.x * 256 + threadIdx.x;
    if (idx >= MR * (HID / 8)) return;
    int h8 = idx % (HID / 8), row = idx / (HID / 8);
    int b = row / TT;
    uint4 q4 = *(const uint4*)(qkv + (size_t)row * NQKV + h8 * 8);
    float num[8], den[8];
#pragma unroll
    for (int j = 0; j < 8; ++j) { num[j] = 0.f; den[j] = 0.f; }
#pragma unroll
    for (int tc = 0; tc < 4; ++tc) {
        const float* np = num_p + (size_t)(tc * BB + b) * HID + h8 * 8;
        const float* dp = den_p + (size_t)(tc * BB + b) * HID + h8 * 8;
#pragma unroll
        for (int j = 0; j < 8; ++j) { num[j] += np[j]; den[j] += dp[j]; }
    }
    unsigned qs[4] = { q4.x, q4.y, q4.z, q4.w };
    unsigned o[4];
#pragma unroll
    for (int w2 = 0; w2 < 4; ++w2) {
        float qa = bf2f((unsigned short)(qs[w2] & 0xffff));
        float qb = bf2f((unsigned short)(qs[w2] >> 16));
        float r0 = num[w2 * 2]     / den[w2 * 2];
        float r1 = num[w2 * 2 + 1] / den[w2 * 2 + 1];
        float y0 = (1.f / (1.f + __expf(-qa))) * r0;
        float y1 = (1.f / (1.f + __expf(-qb))) * r1;
        o[w2] = (unsigned)f2bf(y0) | ((unsigned)f2bf(y1) << 16);
    }
    uint4 ov; ov.x = o[0]; ov.y = o[1]; ov.z = o[2]; ov.w = o[3];
    *(uint4*)(y + (size_t)row * HID + h8 * 8) = ov;
}

// ---------------------------------------------------------------------------
extern "C" void kernel_launch(void* const* d_in, const int* in_sizes, int n_in,
                              void* d_out, int out_size, void* d_ws, size_t ws_size,
                              hipStream_t stream)
{
    const float* x  = (const float*)d_in[0];
    const float* Wq = (const float*)d_in[1];
    const float* bq = (const float*)d_in[2];
    const float* Wk = (const float*)d_in[3];
    const float* bk = (const float*)d_in[4];
    const float* Wv = (const float*)d_in[5];
    const float* bv = (const float*)d_in[6];
    const float* Wo = (const float*)d_in[7];
    const float* bo = (const float*)d_in[8];
    float* out = (float*)d_out;

    char* ws = (char*)d_ws;
    size_t off = 0;
    auto alloc = [&](size_t bytes) -> void* {
        off = (off + 255) & ~(size_t)255;
        void* p = ws + off;
        off += bytes;
        return p;
    };

    unsigned short* xb    = (unsigned short*)alloc((size_t)MR * CC * 2);     // 56.6 MB (reused for y[MR][576])
    unsigned short* WqkvT = (unsigned short*)alloc((size_t)NQKV * CC * 2);   // 2.75 MB
    unsigned short* WoT   = (unsigned short*)alloc((size_t)CC * HID * 2);    // 0.88 MB
    float*          bqkv  = (float*)alloc((size_t)NQKV * 4);
    unsigned short* qkv   = (unsigned short*)alloc((size_t)MR * NQKV * 2);   // 132 MB
    float*          maxk  = (float*)alloc((size_t)TT * HID * 4);             // 1.3 MB
    float*          num_p = (float*)alloc((size_t)4 * BB * HID * 4);
    float*          den_p = (float*)alloc((size_t)4 * BB * HID * 4);
    unsigned short* yb    = xb;   // alias: x_bf16 dead after gemm_qkv

    // 1) weights prep
    {
        int total = NQKV * CC + CC * HID + NQKV;
        prep_kernel<<<dim3((total + 255) / 256), dim3(256), 0, stream>>>(
            Wq, Wk, Wv, Wo, bq, bk, bv, WqkvT, WoT, bqkv);
    }
    // 2) x -> bf16
    {
        int n4 = MR * CC / 4;   // 7077888
        convx_kernel<<<dim3(n4 / 256), dim3(256), 0, stream>>>(x, xb, n4);
    }
    // 3) fused QKV GEMM: [36864,768] x [768,1792] -> bf16 qkv   (grid 144*7=1008)
    gemm4w<0><<<dim3((MR / 256) * (NQKV / 256)), dim3(256), 0, stream>>>(
        xb, WqkvT, (void*)qkv, bqkv, NQKV, CC, CC / 64, NQKV / 256);
    // 4) max over batch
    maxk_kernel<<<dim3(TT * HID / 256), dim3(256), 0, stream>>>(qkv, maxk);
    // 5) num/den partials
    numden_kernel<<<dim3(BB, 4), dim3(HID), 0, stream>>>(qkv, maxk, num_p, den_p);
    // 6) y = sigmoid(q) * num/den (dense stride 576)
    {
        int total = MR * (HID / 8);   // 2654208
        y_kernel<<<dim3(total / 256), dim3(256), 0, stream>>>(qkv, num_p, den_p, yb);
    }
    // 7) output GEMM: [36864,576] x [576,768] + bo -> f32 out   (grid 144*3=432, NT=9)
    gemm4w<1><<<dim3((MR / 256) * (CC / 256)), dim3(256), 0, stream>>>(
        yb, WoT, (void*)out, bo, CC, HID, HID / 64, CC / 256);
}